// Round 13
// baseline (2233.235 us; speedup 1.0000x reference)
//
#include <hip/hip_runtime.h>
#include <hip/hip_bf16.h>
#include <cstdint>

#define B 2048
#define NL 32
#define FEAT 512
#define HID 512
#define HW 64
#define OUTSZ 42
#define G3 1536
#define LDIH 554   // gru_w_ih row stride
#define MB 16      // batch rows per block
#define NBLK (B/MB)   // 128
#define LDX 584    // lds_x row stride
#define LDH 520    // o1s row stride
#define CHW 16384  // bf16 elements per 32KB chunk

typedef __bf16 bf16x8 __attribute__((ext_vector_type(8)));
typedef unsigned short u16x8 __attribute__((ext_vector_type(8)));
typedef float f32x4 __attribute__((ext_vector_type(4)));
typedef __hip_bfloat16 bf16_t;

#define MFMA(a,b,c) __builtin_amdgcn_mfma_f32_16x16x32_bf16(a,b,c,0,0,0)

static __device__ __forceinline__ float sigmoidf_(float x){ return 1.f/(1.f+__expf(-x)); }
static __device__ __forceinline__ float bf_lo(uint32_t u){
  union { uint32_t i; float f; } c; c.i = u << 16; return c.f;
}
static __device__ __forceinline__ float bf_hi(uint32_t u){
  union { uint32_t i; float f; } c; c.i = u & 0xffff0000u; return c.f;
}

// ---------------- one-time weight prep into STAGING layouts (unchanged, verified) ----
// sA[54][512][32]: chunk (k0,g) at c=k0*3+g; row rp; granule gq holds
//   k-quarter half = gq ^ ((rp>>1)&3). sB[16][512][32]: lin1 chunks.
// sC[2][64][256]: lin2 k-halves, granule s holds g = s^(j&7).
// w_ssn[512][64]; w_ih512b, bias_comb: preamble GEMM.
__global__ __launch_bounds__(256) void prep4_kernel(
    const float* __restrict__ w_ih, const float* __restrict__ w_hh,
    const float* __restrict__ lin1_w, const float* __restrict__ lin2_w,
    const float* __restrict__ b_ih, const float* __restrict__ b_hh,
    bf16_t* __restrict__ sA, bf16_t* __restrict__ sB, bf16_t* __restrict__ sC,
    bf16_t* __restrict__ w_ssn, bf16_t* __restrict__ w_ih512b,
    float* __restrict__ bias_comb){
  const int NA = 54*CHW, NB2 = 16*CHW, NC2 = 2*CHW, NS = 512*64, NI = G3*512;
  const int total = NA+NB2+NC2+NS+NI+G3;
  for (int idx = blockIdx.x*256 + threadIdx.x; idx < total; idx += gridDim.x*256){
    int i = idx;
    if (i < NA){
      int c = i/CHW, r2 = i%CHW, rp = r2>>5, kk = r2&31, gq = kk>>3, e = kk&7;
      int k0 = c/3, g = c%3;
      int half = gq ^ ((rp>>1)&3);
      int orow = g*512 + rp;
      int k = k0*32 + half*8 + e;
      float v = (k < 512) ? w_hh[orow*512 + k]
              : ((k < 512+OUTSZ && g < 2) ? w_ih[(size_t)orow*LDIH + k] : 0.f);
      sA[i] = __float2bfloat16(v);
    } else if ((i -= NA) < NB2){
      int c = i/CHW, r2 = i%CHW, rp = r2>>5, kk = r2&31, gq = kk>>3, e = kk&7;
      int half = gq ^ ((rp>>1)&3);
      sB[i] = __float2bfloat16(lin1_w[rp*512 + c*32 + half*8 + e]);
    } else if ((i -= NB2) < NC2){
      int n = i/CHW, r2 = i%CHW, j = r2>>8, kk = r2&255, s = kk>>3, e = kk&7;
      int g = s ^ (j & 7);
      int k = n*256 + g*8 + e;
      float v = (j < OUTSZ) ? lin2_w[j*512 + k] : 0.f;
      sC[i] = __float2bfloat16(v);
    } else if ((i -= NC2) < NS){
      int j = i>>6, k = i&63;
      float v = (k < OUTSZ) ? w_ih[(size_t)(1024+j)*LDIH + 512 + k] : 0.f;
      w_ssn[i] = __float2bfloat16(v);
    } else if ((i -= NS) < NI){
      int r = i>>9, c = i&511;
      w_ih512b[i] = __float2bfloat16(w_ih[(size_t)r*LDIH + c]);
    } else {
      int j = i - NI;
      bias_comb[j] = b_ih[j] + (j < 1024 ? b_hh[j] : 0.f);
    }
  }
}

// ---------------- attention precompute (step-invariant) ----------------
__global__ __launch_bounds__(256) void att_kernel(const float* __restrict__ feat,
                                                  const float* __restrict__ att_w,
                                                  bf16_t* __restrict__ att_feat){
  int b = blockIdx.x;
  const float* fb = feat + (size_t)b * FEAT * HW;
  __shared__ float part[4][64];
  __shared__ float attv[64];
  int t = threadIdx.x;
  int s = t & 63, q = t >> 6;
  float acc = 0.f;
  for (int c = q*128; c < q*128 + 128; ++c)
    acc = fmaf(fb[c*HW + s], att_w[c], acc);
  part[q][s] = acc;
  __syncthreads();
  if (t < 64){
    float v = part[0][t] + part[1][t] + part[2][t] + part[3][t];
    float m = v;
    for (int o = 32; o > 0; o >>= 1) m = fmaxf(m, __shfl_xor(m, o));
    float e = __expf(v - m);
    float ssum = e;
    for (int o = 32; o > 0; o >>= 1) ssum += __shfl_xor(ssum, o);
    attv[t] = e / ssum * 2.0f;   // * BETA
  }
  __syncthreads();
  for (int c = t; c < FEAT; c += 256){
    const float4* row = (const float4*)(fb + c*HW);
    float a2 = 0.f;
    #pragma unroll
    for (int k = 0; k < 16; ++k){
      float4 v4 = row[k];
      a2 = fmaf(v4.x, attv[k*4+0], a2);
      a2 = fmaf(v4.y, attv[k*4+1], a2);
      a2 = fmaf(v4.z, attv[k*4+2], a2);
      a2 = fmaf(v4.w, attv[k*4+3], a2);
    }
    att_feat[(size_t)b*FEAT + c] = __float2bfloat16(a2);
  }
}

// ---------------- bf16 MFMA GEMM (NT) for gi_base preamble; bf16 output ----------------
__global__ __launch_bounds__(256) void gemm_mfma_bf(const bf16_t* __restrict__ A,
                                                    const bf16_t* __restrict__ W,
                                                    const float* __restrict__ bias,
                                                    bf16_t* __restrict__ C,
                                                    int K, int lda, int ldw, int ldc){
  const int tid = threadIdx.x;
  const int w = tid >> 6, lane = tid & 63;
  const int r = lane & 15, half = lane >> 4;
  const int m_base = blockIdx.y * 64;
  const int n_base = blockIdx.x * 64 + w * 16;
  const bf16_t* Ap = A + (size_t)(m_base + r)*lda + half*8;
  const bf16_t* Wp = W + (size_t)(n_base + r)*ldw + half*8;
  f32x4 acc[4] = {};
  for (int k0 = 0; k0 < K; k0 += 32){
    bf16x8 bfrag = *(const bf16x8*)(Wp + k0);
    #pragma unroll
    for (int i = 0; i < 4; ++i){
      bf16x8 afrag = *(const bf16x8*)(Ap + (size_t)i*16*lda + k0);
      acc[i] = MFMA(afrag, bfrag, acc[i]);
    }
  }
  const float bv = bias ? bias[n_base + r] : 0.f;
  #pragma unroll
  for (int i = 0; i < 4; ++i)
    #pragma unroll
    for (int q = 0; q < 4; ++q)
      C[(size_t)(m_base + i*16 + half*4 + q)*ldc + n_base + r] =
          __float2bfloat16(acc[i][q] + bv);
}

// ---------------- the 32-step scan: L2->VGPR 4-buffer weight pipeline ----------------
// 128 blocks x 512 threads (8 waves). Weights stream L2 -> registers directly
// (no LDS round-trip, no per-chunk barriers). gi_base register-resident as
// packed bf16 (24 VGPRs) so NOTHING per-step is re-read from global except the
// weight stream -> per-XCD L2 set ~2.3MB, fully resident. 4 barriers/step.
__global__ __launch_bounds__(512, 2) void mega10_kernel(
    const bf16_t* __restrict__ gi16,       // [B][1536] bf16, incl biases
    const bf16_t* __restrict__ sA,
    const bf16_t* __restrict__ sB,
    const bf16_t* __restrict__ sC,
    const bf16_t* __restrict__ w_ssn,
    const float* __restrict__ lin1_b,
    const float* __restrict__ lin2_b,
    const float* __restrict__ b_hh,
    const float* __restrict__ gt,
    const int* __restrict__ line_prob,
    const float* __restrict__ sample_prob,
    float* __restrict__ out){
  __shared__ bf16_t lds_x[MB][LDX];      // [h(512) | ss(42) | zeros]
  __shared__ bf16_t o1s[MB][LDH];
  const int tid = threadIdx.x;
  const int wv = tid >> 6, l = tid & 63;
  const int lr = l & 15, half = l >> 4;
  const int m0 = blockIdx.x * MB;
  const int colbase = wv * 64;
  const int rowoff = (colbase + lr)*32 + (half ^ ((lr >> 1) & 3))*8;

  for (int i = tid; i < MB*LDX/2; i += 512) ((uint32_t*)lds_x)[i] = 0u;

  // ---- gi_base slice, packed bf16: gip[gate][ti][p] holds rows q=2p,2p+1 ----
  uint32_t gip[3][4][2];
  #pragma unroll
  for (int g = 0; g < 3; ++g)
    #pragma unroll
    for (int ti = 0; ti < 4; ++ti)
      #pragma unroll
      for (int p = 0; p < 2; ++p){
        const bf16_t* gp = gi16 + (size_t)(m0 + half*4 + 2*p)*G3
                          + g*512 + colbase + ti*16 + lr;
        uint32_t lo = *(const uint16_t*)gp;
        uint32_t hi = *(const uint16_t*)(gp + G3);
        gip[g][ti][p] = lo | (hi << 16);
      }

  float bhn[4], lb1[4];
  #pragma unroll
  for (int ti = 0; ti < 4; ++ti){
    bhn[ti] = b_hh[1024 + colbase + ti*16 + lr];
    lb1[ti] = lin1_b[colbase + ti*16 + lr];
  }
  const int j3 = wv*16 + lr;
  const float b2c = (wv < 3 && j3 < OUTSZ) ? lin2_b[j3] : 0.f;
  bf16x8 sfr[4][2];
  #pragma unroll
  for (int ti = 0; ti < 4; ++ti)
    #pragma unroll
    for (int ks = 0; ks < 2; ++ks)
      sfr[ti][ks] = *(const bf16x8*)(w_ssn + (size_t)(colbase + ti*16 + lr)*64 + ks*32 + half*8);

  float hp[4][4] = {};

  // ---- 4-buffer register pipeline; prologue: chunks 0..3 -> buffers 0..3 ----
  bf16x8 Wb[4][4];
  #pragma unroll
  for (int c = 0; c < 4; ++c){
    const bf16_t* s = sA + (size_t)c*CHW + rowoff;
    #pragma unroll
    for (int ti = 0; ti < 4; ++ti)
      Wb[c][ti] = *(const bf16x8*)(s + ti*512);
  }

  __syncthreads();

  #pragma unroll 1
  for (int t = 0; t < NL; ++t){
    // ---- ssn first (reads ss cols; weights persistent in VGPRs) ----
    f32x4 accS[4] = {};
    #pragma unroll
    for (int ks = 0; ks < 2; ++ks){
      bf16x8 a2 = *(const bf16x8*)&lds_x[lr][512 + ks*32 + half*8];
      #pragma unroll
      for (int ti = 0; ti < 4; ++ti)
        accS[ti] = MFMA(a2, sfr[ti][ks], accS[ti]);
    }

    // ========== phase A: 54 chunks, 12-unrolled (lcm of 3 gates x 4 buffers) ==========
    f32x4 accA[3][4] = {};
    #pragma unroll 1
    for (int m = 0; m < 4; ++m){          // chunks 0..47
      #pragma unroll
      for (int u = 0; u < 12; ++u){
        const int g = u % 3, jb = u % 4, k0o = u / 3;
        bf16x8 a = *(const bf16x8*)&lds_x[lr][(m*4 + k0o)*32 + half*8];
        #pragma unroll
        for (int ti = 0; ti < 4; ++ti)
          accA[g][ti] = MFMA(a, Wb[jb][ti], accA[g][ti]);
        const bf16_t* s = sA + (size_t)(12*m + u + 4)*CHW + rowoff;  // max 51 < 54
        #pragma unroll
        for (int ti = 0; ti < 4; ++ti)
          Wb[jb][ti] = *(const bf16x8*)(s + ti*512);
      }
    }
    #pragma unroll
    for (int u = 0; u < 6; ++u){          // chunks 48..53; reload 52..57
      const int g = u % 3, jb = u % 4;
      bf16x8 a = *(const bf16x8*)&lds_x[lr][(16 + u/3)*32 + half*8];
      #pragma unroll
      for (int ti = 0; ti < 4; ++ti)
        accA[g][ti] = MFMA(a, Wb[jb][ti], accA[g][ti]);
      const bf16_t* s = (u < 2) ? (sA + (size_t)(52 + u)*CHW + rowoff)
                                : (sB + (size_t)(u - 2)*CHW + rowoff);
      #pragma unroll
      for (int ti = 0; ti < 4; ++ti)
        Wb[jb][ti] = *(const bf16x8*)(s + ti*512);
    }
    __syncthreads();   // (1) lds_x reads done before gates rewrite h-cols

    // ---- gates (gi unpacked from packed bf16 registers) ----
    #pragma unroll
    for (int ti = 0; ti < 4; ++ti)
      #pragma unroll
      for (int p = 0; p < 2; ++p)
        #pragma unroll
        for (int qq = 0; qq < 2; ++qq){
          const int q = 2*p + qq;
          float gr = qq ? bf_hi(gip[0][ti][p]) : bf_lo(gip[0][ti][p]);
          float gz = qq ? bf_hi(gip[1][ti][p]) : bf_lo(gip[1][ti][p]);
          float gn = qq ? bf_hi(gip[2][ti][p]) : bf_lo(gip[2][ti][p]);
          float ir = accA[0][ti][q] + gr;
          float iz = accA[1][ti][q] + gz;
          float hn = accA[2][ti][q] + bhn[ti];
          float gnn = gn + accS[ti][q];
          float r = sigmoidf_(ir);
          float z = sigmoidf_(iz);
          float n = tanhf(gnn + r*hn);
          float hv = (1.f - z)*n + z*hp[ti][q];
          hp[ti][q] = hv;
          lds_x[half*4 + q][colbase + ti*16 + lr] = __float2bfloat16(hv);
        }
    __syncthreads();   // (2) h ready for phase B

    // ========== phase B: 16 chunks (lin1); buffers (i+2)%4 ==========
    f32x4 accB[4] = {};
    #pragma unroll
    for (int i = 0; i < 16; ++i){
      const int jb = (i + 2) % 4;
      union { u16x8 u; bf16x8 b; } va;
      va.u = *(const u16x8*)&lds_x[lr][i*32 + half*8];
      #pragma unroll
      for (int e = 0; e < 8; ++e)
        if (va.u[e] & 0x8000) va.u[e] = 0;       // relu on bf16 sign
      #pragma unroll
      for (int ti = 0; ti < 4; ++ti)
        accB[ti] = MFMA(va.b, Wb[jb][ti], accB[ti]);
      if (i < 12){
        const bf16_t* s = sB + (size_t)(4 + i)*CHW + rowoff;
        #pragma unroll
        for (int ti = 0; ti < 4; ++ti)
          Wb[jb][ti] = *(const bf16x8*)(s + ti*512);
      }
    }
    // burst restart: next step's chunks 0..3 -> buffers 0..3 (covered by C+barriers)
    #pragma unroll
    for (int c = 0; c < 4; ++c){
      const bf16_t* s = sA + (size_t)c*CHW + rowoff;
      #pragma unroll
      for (int ti = 0; ti < 4; ++ti)
        Wb[c][ti] = *(const bf16x8*)(s + ti*512);
    }
    #pragma unroll
    for (int ti = 0; ti < 4; ++ti)
      #pragma unroll
      for (int q = 0; q < 4; ++q)
        o1s[half*4 + q][colbase + ti*16 + lr] =
            __float2bfloat16(fmaxf(accB[ti][q] + lb1[ti], 0.f));
    __syncthreads();   // (3) o1s ready

    // ========== phase C: lin2 (direct loads, waves 0..2) + outputs + ss ==========
    if (wv < 3){
      f32x4 accC = {};
      #pragma unroll
      for (int n = 0; n < 2; ++n)
        #pragma unroll
        for (int k0 = 0; k0 < 8; ++k0){
          bf16x8 a = *(const bf16x8*)&o1s[lr][(n*8 + k0)*32 + half*8];
          int sg = (k0*4 + half) ^ (j3 & 7);
          bf16x8 bf = *(const bf16x8*)(sC + (size_t)n*CHW + j3*256 + sg*8);
          accC = MFMA(a, bf, accC);
        }
      #pragma unroll
      for (int q = 0; q < 4; ++q){
        float val = accC[q] + b2c;
        int row = half*4 + q;
        int bm = m0 + row;
        if (j3 < 40){
          out[((size_t)bm*NL + t)*40 + j3] = val;
        } else if (j3 < 42){
          float other = __shfl_xor(val, 1);
          float mx = fmaxf(val, other);
          float e0 = __expf(val - mx), e1 = __expf(other - mx);
          out[(size_t)B*NL*40 + ((size_t)bm*NL + t)*2 + (j3 - 40)] = e0/(e0 + e1);
        }
        if (t + 1 < NL && j3 < OUTSZ){
          bool up = sample_prob[(size_t)(t+1)*B + bm] < 0.1f;
          float gtv;
          if (j3 < 40) gtv = gt[((size_t)bm*NL + t)*40 + j3];
          else {
            float pv = (float)line_prob[bm*NL + t];
            gtv = (j3 == 40) ? 1.f - pv : pv;
          }
          lds_x[row][512 + j3] = __float2bfloat16(up ? val : gtv);
        }
      }
    }
    __syncthreads();   // (4) ss ready for next step
  }
}

extern "C" void kernel_launch(void* const* d_in, const int* in_sizes, int n_in,
                              void* d_out, int out_size, void* d_ws, size_t ws_size,
                              hipStream_t stream) {
  const float* img         = (const float*)d_in[0];
  const float* gt          = (const float*)d_in[1];
  const int*   line_prob   = (const int*)d_in[2];
  const float* sample_prob = (const float*)d_in[3];
  const float* att_w       = (const float*)d_in[4];
  // d_in[5] att_b: unused — softmax shift-invariance cancels it
  const float* w_ih        = (const float*)d_in[6];
  const float* w_hh        = (const float*)d_in[7];
  const float* b_ih        = (const float*)d_in[8];
  const float* b_hh        = (const float*)d_in[9];
  const float* lin1_w      = (const float*)d_in[10];
  const float* lin1_b      = (const float*)d_in[11];
  const float* lin2_w      = (const float*)d_in[12];
  const float* lin2_b      = (const float*)d_in[13];
  float* out = (float*)d_out;

  char* p = (char*)d_ws;
  auto alloc = [&](size_t bytes){ void* q = p; p += (bytes + 255) & ~(size_t)255; return q; };
  bf16_t* gi16      = (bf16_t*)alloc((size_t)B*G3*2);
  bf16_t* att_bf    = (bf16_t*)alloc((size_t)B*FEAT*2);
  bf16_t* sA        = (bf16_t*)alloc((size_t)54*CHW*2);
  bf16_t* sB        = (bf16_t*)alloc((size_t)16*CHW*2);
  bf16_t* sC        = (bf16_t*)alloc((size_t)2*CHW*2);
  bf16_t* w_ssn     = (bf16_t*)alloc((size_t)512*64*2);
  bf16_t* w_ih512b  = (bf16_t*)alloc((size_t)G3*512*2);
  float*  bias_comb = (float*)alloc((size_t)G3*4);

  prep4_kernel<<<4096, 256, 0, stream>>>(w_ih, w_hh, lin1_w, lin2_w, b_ih, b_hh,
                                         sA, sB, sC, w_ssn, w_ih512b, bias_comb);
  att_kernel<<<B, 256, 0, stream>>>(img, att_w, att_bf);
  gemm_mfma_bf<<<dim3(G3/64, B/64), 256, 0, stream>>>(att_bf, w_ih512b, bias_comb, gi16,
                                                      512, 512, 512, G3);
  mega10_kernel<<<NBLK, 512, 0, stream>>>(gi16, sA, sB, sC, w_ssn, lin1_b, lin2_b,
                                          b_hh, gt, line_prob, sample_prob, out);
}

// Round 14
// 1507.510 us; speedup vs baseline: 1.4814x; 1.4814x over previous
//
#include <hip/hip_runtime.h>
#include <hip/hip_bf16.h>
#include <cstdint>

#define B 2048
#define NL 32
#define FEAT 512
#define HID 512
#define HW 64
#define OUTSZ 42
#define G3 1536
#define LDIH 554   // gru_w_ih row stride
#define MB 16      // batch rows per block
#define NBLK (B/MB)   // 128
#define LDX 584    // lds_x row stride
#define LDH 520    // o1s row stride
#define CPS 72     // chunks per step: 54 A + 16 B + 2 C
#define CHW 16384  // bf16 elements per 32KB chunk

typedef __bf16 bf16x8 __attribute__((ext_vector_type(8)));
typedef unsigned short u16x8 __attribute__((ext_vector_type(8)));
typedef float f32x4 __attribute__((ext_vector_type(4)));
typedef __hip_bfloat16 bf16_t;

#define MFMA(a,b,c) __builtin_amdgcn_mfma_f32_16x16x32_bf16(a,b,c,0,0,0)

// Counted-vmcnt sync: wait for the chunk we are about to consume (vmcnt(4)
// leaves the next chunk's 4 loads in flight), drain this wave's own LDS ops
// (makes our ds_writes visible / our ds_reads complete), then RAW s_barrier.
// __syncthreads() is NOT used in the hot loop: the compiler would emit
// s_waitcnt vmcnt(0) before it, draining the prefetch pipeline every chunk.
#define CHUNK_SYNC() do {                                            \
    asm volatile("s_waitcnt vmcnt(4)" ::: "memory");                 \
    asm volatile("s_waitcnt lgkmcnt(0)" ::: "memory");               \
    __builtin_amdgcn_s_barrier();                                    \
  } while (0)

static __device__ __forceinline__ float sigmoidf_(float x){ return 1.f/(1.f+__expf(-x)); }

static __device__ __forceinline__ void gld16(const bf16_t* g, bf16_t* l){
  __builtin_amdgcn_global_load_lds(
      (const __attribute__((address_space(1))) void*)g,
      (__attribute__((address_space(3))) void*)l, 16, 0, 0);
}

// ---------------- one-time weight prep into STAGING layouts (verified) ----------------
// sA[54][512][32]: chunk (k0,g) at c=k0*3+g; row rp; granule gq holds
//   k-quarter half = gq ^ ((rp>>1)&3)  -> conflict-free wave-wide ds_read_b128.
// sB[16][512][32]: lin1 chunks. sC[2][64][256]: lin2 k-halves, granule s holds
//   g = s^(j&7). w_ssn[512][64]; w_ih512b, bias_comb: preamble GEMM.
__global__ __launch_bounds__(256) void prep4_kernel(
    const float* __restrict__ w_ih, const float* __restrict__ w_hh,
    const float* __restrict__ lin1_w, const float* __restrict__ lin2_w,
    const float* __restrict__ b_ih, const float* __restrict__ b_hh,
    bf16_t* __restrict__ sA, bf16_t* __restrict__ sB, bf16_t* __restrict__ sC,
    bf16_t* __restrict__ w_ssn, bf16_t* __restrict__ w_ih512b,
    float* __restrict__ bias_comb){
  const int NA = 54*CHW, NB2 = 16*CHW, NC2 = 2*CHW, NS = 512*64, NI = G3*512;
  const int total = NA+NB2+NC2+NS+NI+G3;
  for (int idx = blockIdx.x*256 + threadIdx.x; idx < total; idx += gridDim.x*256){
    int i = idx;
    if (i < NA){
      int c = i/CHW, r2 = i%CHW, rp = r2>>5, kk = r2&31, gq = kk>>3, e = kk&7;
      int k0 = c/3, g = c%3;
      int half = gq ^ ((rp>>1)&3);
      int orow = g*512 + rp;
      int k = k0*32 + half*8 + e;
      float v = (k < 512) ? w_hh[orow*512 + k]
              : ((k < 512+OUTSZ && g < 2) ? w_ih[(size_t)orow*LDIH + k] : 0.f);
      sA[i] = __float2bfloat16(v);
    } else if ((i -= NA) < NB2){
      int c = i/CHW, r2 = i%CHW, rp = r2>>5, kk = r2&31, gq = kk>>3, e = kk&7;
      int half = gq ^ ((rp>>1)&3);
      sB[i] = __float2bfloat16(lin1_w[rp*512 + c*32 + half*8 + e]);
    } else if ((i -= NB2) < NC2){
      int n = i/CHW, r2 = i%CHW, j = r2>>8, kk = r2&255, s = kk>>3, e = kk&7;
      int g = s ^ (j & 7);
      int k = n*256 + g*8 + e;
      float v = (j < OUTSZ) ? lin2_w[j*512 + k] : 0.f;
      sC[i] = __float2bfloat16(v);
    } else if ((i -= NC2) < NS){
      int j = i>>6, k = i&63;
      float v = (k < OUTSZ) ? w_ih[(size_t)(1024+j)*LDIH + 512 + k] : 0.f;
      w_ssn[i] = __float2bfloat16(v);
    } else if ((i -= NS) < NI){
      int r = i>>9, c = i&511;
      w_ih512b[i] = __float2bfloat16(w_ih[(size_t)r*LDIH + c]);
    } else {
      int j = i - NI;
      bias_comb[j] = b_ih[j] + (j < 1024 ? b_hh[j] : 0.f);
    }
  }
}

// ---------------- attention precompute (step-invariant) ----------------
__global__ __launch_bounds__(256) void att_kernel(const float* __restrict__ feat,
                                                  const float* __restrict__ att_w,
                                                  bf16_t* __restrict__ att_feat){
  int b = blockIdx.x;
  const float* fb = feat + (size_t)b * FEAT * HW;
  __shared__ float part[4][64];
  __shared__ float attv[64];
  int t = threadIdx.x;
  int s = t & 63, q = t >> 6;
  float acc = 0.f;
  for (int c = q*128; c < q*128 + 128; ++c)
    acc = fmaf(fb[c*HW + s], att_w[c], acc);
  part[q][s] = acc;
  __syncthreads();
  if (t < 64){
    float v = part[0][t] + part[1][t] + part[2][t] + part[3][t];
    float m = v;
    for (int o = 32; o > 0; o >>= 1) m = fmaxf(m, __shfl_xor(m, o));
    float e = __expf(v - m);
    float ssum = e;
    for (int o = 32; o > 0; o >>= 1) ssum += __shfl_xor(ssum, o);
    attv[t] = e / ssum * 2.0f;   // * BETA
  }
  __syncthreads();
  for (int c = t; c < FEAT; c += 256){
    const float4* row = (const float4*)(fb + c*HW);
    float a2 = 0.f;
    #pragma unroll
    for (int k = 0; k < 16; ++k){
      float4 v4 = row[k];
      a2 = fmaf(v4.x, attv[k*4+0], a2);
      a2 = fmaf(v4.y, attv[k*4+1], a2);
      a2 = fmaf(v4.z, attv[k*4+2], a2);
      a2 = fmaf(v4.w, attv[k*4+3], a2);
    }
    att_feat[(size_t)b*FEAT + c] = __float2bfloat16(a2);
  }
}

// ---------------- bf16 MFMA GEMM (NT) for gi_base preamble ----------------
__global__ __launch_bounds__(256) void gemm_mfma(const bf16_t* __restrict__ A,
                                                 const bf16_t* __restrict__ W,
                                                 const float* __restrict__ bias,
                                                 float* __restrict__ C,
                                                 int K, int lda, int ldw, int ldc){
  const int tid = threadIdx.x;
  const int w = tid >> 6, lane = tid & 63;
  const int r = lane & 15, half = lane >> 4;
  const int m_base = blockIdx.y * 64;
  const int n_base = blockIdx.x * 64 + w * 16;
  const bf16_t* Ap = A + (size_t)(m_base + r)*lda + half*8;
  const bf16_t* Wp = W + (size_t)(n_base + r)*ldw + half*8;
  f32x4 acc[4] = {};
  for (int k0 = 0; k0 < K; k0 += 32){
    bf16x8 bfrag = *(const bf16x8*)(Wp + k0);
    #pragma unroll
    for (int i = 0; i < 4; ++i){
      bf16x8 afrag = *(const bf16x8*)(Ap + (size_t)i*16*lda + k0);
      acc[i] = MFMA(afrag, bfrag, acc[i]);
    }
  }
  const float bv = bias ? bias[n_base + r] : 0.f;
  #pragma unroll
  for (int i = 0; i < 4; ++i)
    #pragma unroll
    for (int q = 0; q < 4; ++q)
      C[(size_t)(m_base + i*16 + half*4 + q)*ldc + n_base + r] = acc[i][q] + bv;
}

// ---------------- the 32-step scan: staged pipeline, RAW barriers, counted vmcnt ----
// Identical math/layout to the verified mega7 (1391us, FETCH 21MB). Changes:
// (1) every __syncthreads -> CHUNK_SYNC (counted vmcnt + raw s_barrier), so
//     prefetched chunks stay in flight across barriers (T3/T4 recipe);
// (2) issue(gc+2) moved to right after the barrier (2-window transfer lead).
__global__ __launch_bounds__(512, 2) void mega11_kernel(
    const float* __restrict__ gi_base,
    const bf16_t* __restrict__ sA,
    const bf16_t* __restrict__ sB,
    const bf16_t* __restrict__ sC,
    const bf16_t* __restrict__ w_ssn,
    const float* __restrict__ lin1_b,
    const float* __restrict__ lin2_b,
    const float* __restrict__ b_hh,
    const float* __restrict__ gt,
    const int* __restrict__ line_prob,
    const float* __restrict__ sample_prob,
    float* __restrict__ out){
  __shared__ bf16_t ring[3*CHW];         // 3 x 32KB
  __shared__ bf16_t lds_x[MB][LDX];      // [h(512) | ss(42) | zeros]
  __shared__ bf16_t o1s[MB][LDH];
  const int tid = threadIdx.x;
  const int wv = tid >> 6, l = tid & 63;
  const int lr = l & 15, half = l >> 4;
  const int m0 = blockIdx.x * MB;
  const int colbase = wv * 64;
  const int rowoff = (colbase + lr)*32 + (half ^ ((lr >> 1) & 3))*8;

  for (int i = tid; i < MB*LDX/2; i += 512) ((uint32_t*)lds_x)[i] = 0u;

  // ---- register-resident gi_base slice: 4(ti) x 4(q) x 3 gates ----
  float gir[4][4], giz[4][4], gin_[4][4];
  #pragma unroll
  for (int ti = 0; ti < 4; ++ti)
    #pragma unroll
    for (int q = 0; q < 4; ++q){
      const float* gp = gi_base + (size_t)(m0 + half*4 + q)*G3 + colbase + ti*16 + lr;
      gir[ti][q]  = gp[0];
      giz[ti][q]  = gp[512];
      gin_[ti][q] = gp[1024];
    }
  float bhn[4], lb1[4];
  #pragma unroll
  for (int ti = 0; ti < 4; ++ti){
    bhn[ti] = b_hh[1024 + colbase + ti*16 + lr];
    lb1[ti] = lin1_b[colbase + ti*16 + lr];
  }
  const int j3 = wv*16 + lr;
  const float b2c = (wv < 3 && j3 < OUTSZ) ? lin2_b[j3] : 0.f;
  bf16x8 sfr[4][2];
  #pragma unroll
  for (int ti = 0; ti < 4; ++ti)
    #pragma unroll
    for (int ks = 0; ks < 2; ++ks)
      sfr[ti][ks] = *(const bf16x8*)(w_ssn + (size_t)(colbase + ti*16 + lr)*64 + ks*32 + half*8);

  float hp[4][4] = {};

  auto issue = [&](uint32_t g){
    const bf16_t* src = sA;              // dummy tail issues read sA
    if (g < (uint32_t)NL*CPS){
      uint32_t c = g % CPS;
      src = (c < 54) ? sA + (size_t)c*CHW
          : (c < 70) ? sB + (size_t)(c-54)*CHW
                     : sC + (size_t)(c-70)*CHW;
    }
    bf16_t* dst = ring + (g % 3)*CHW;
    #pragma unroll
    for (int i = 0; i < 4; ++i)
      gld16(src + tid*8 + i*4096, dst + tid*8 + i*4096);
  };

  uint32_t gc = 0;
  issue(0); issue(1);

  #pragma unroll 1
  for (int t = 0; t < NL; ++t){
    // ================= phase A: 54 chunks (k0-major, gate-minor) =================
    f32x4 accA[3][4] = {};
    #pragma unroll 1
    for (int k0 = 0; k0 < 18; ++k0){
      bf16x8 a;
      #pragma unroll
      for (int g = 0; g < 3; ++g){
        CHUNK_SYNC();
        issue(gc + 2);                  // slot(gc+2)=slot(gc-1): freed by this barrier
        a = *(const bf16x8*)&lds_x[lr][k0*32 + half*8];
        const bf16_t* S = ring + (gc % 3)*CHW;
        #pragma unroll
        for (int ti = 0; ti < 4; ++ti){
          bf16x8 bf = *(const bf16x8*)&S[rowoff + ti*512];
          accA[g][ti] = MFMA(a, bf, accA[g][ti]);
        }
        ++gc;
      }
    }

    // ---- ssn (weights in VGPRs; reads ss cols 512.. — disjoint from h writes) ----
    f32x4 accS[4] = {};
    #pragma unroll
    for (int ks = 0; ks < 2; ++ks){
      bf16x8 a2 = *(const bf16x8*)&lds_x[lr][512 + ks*32 + half*8];
      #pragma unroll
      for (int ti = 0; ti < 4; ++ti)
        accS[ti] = MFMA(a2, sfr[ti][ks], accS[ti]);
    }

    // ---- gates (write h cols 0..511; pending A reads are cols 544+, disjoint) ----
    #pragma unroll
    for (int ti = 0; ti < 4; ++ti)
      #pragma unroll
      for (int q = 0; q < 4; ++q){
        float ir = accA[0][ti][q] + gir[ti][q];
        float iz = accA[1][ti][q] + giz[ti][q];
        float hn = accA[2][ti][q] + bhn[ti];
        float gn = gin_[ti][q] + accS[ti][q];
        float r = sigmoidf_(ir);
        float z = sigmoidf_(iz);
        float n = tanhf(gn + r*hn);
        float hv = (1.f - z)*n + z*hp[ti][q];
        hp[ti][q] = hv;
        lds_x[half*4 + q][colbase + ti*16 + lr] = __float2bfloat16(hv);
      }

    // ================= phase B: 16 chunks (lin1) =================
    f32x4 accB[4] = {};
    #pragma unroll 1
    for (int cb = 0; cb < 16; ++cb){
      CHUNK_SYNC();                     // lgkmcnt(0) publishes gates' h writes
      issue(gc + 2);
      union { u16x8 u; bf16x8 b; } va;
      va.u = *(const u16x8*)&lds_x[lr][cb*32 + half*8];
      #pragma unroll
      for (int e = 0; e < 8; ++e)
        if (va.u[e] & 0x8000) va.u[e] = 0;       // relu on bf16
      const bf16_t* S = ring + (gc % 3)*CHW;
      #pragma unroll
      for (int ti = 0; ti < 4; ++ti){
        bf16x8 bf = *(const bf16x8*)&S[rowoff + ti*512];
        accB[ti] = MFMA(va.b, bf, accB[ti]);
      }
      ++gc;
    }
    #pragma unroll
    for (int ti = 0; ti < 4; ++ti)
      #pragma unroll
      for (int q = 0; q < 4; ++q)
        o1s[half*4 + q][colbase + ti*16 + lr] =
            __float2bfloat16(fmaxf(accB[ti][q] + lb1[ti], 0.f));

    // ================= phase C: 2 chunks (lin2) =================
    f32x4 accC = {};
    #pragma unroll
    for (int n = 0; n < 2; ++n){
      CHUNK_SYNC();                     // publishes o1s writes
      issue(gc + 2);
      if (wv < 3){
        const bf16_t* S = ring + (gc % 3)*CHW;
        #pragma unroll
        for (int k0 = 0; k0 < 8; ++k0){
          bf16x8 a = *(const bf16x8*)&o1s[lr][(n*8 + k0)*32 + half*8];
          int sg = (k0*4 + half) ^ (j3 & 7);
          bf16x8 bf = *(const bf16x8*)&S[j3*256 + sg*8];
          accC = MFMA(a, bf, accC);
        }
      }
      ++gc;
    }
    // outputs + ss_{t+1} (ss cols read next at t+1's ssn, many barriers away)
    if (wv < 3){
      #pragma unroll
      for (int q = 0; q < 4; ++q){
        float val = accC[q] + b2c;
        int row = half*4 + q;
        int bm = m0 + row;
        if (j3 < 40){
          out[((size_t)bm*NL + t)*40 + j3] = val;
        } else if (j3 < 42){
          float other = __shfl_xor(val, 1);
          float mx = fmaxf(val, other);
          float e0 = __expf(val - mx), e1 = __expf(other - mx);
          out[(size_t)B*NL*40 + ((size_t)bm*NL + t)*2 + (j3 - 40)] = e0/(e0 + e1);
        }
        if (t + 1 < NL && j3 < OUTSZ){
          bool up = sample_prob[(size_t)(t+1)*B + bm] < 0.1f;
          float gtv;
          if (j3 < 40) gtv = gt[((size_t)bm*NL + t)*40 + j3];
          else {
            float pv = (float)line_prob[bm*NL + t];
            gtv = (j3 == 40) ? 1.f - pv : pv;
          }
          lds_x[row][512 + j3] = __float2bfloat16(up ? val : gtv);
        }
      }
    }
  }
}

extern "C" void kernel_launch(void* const* d_in, const int* in_sizes, int n_in,
                              void* d_out, int out_size, void* d_ws, size_t ws_size,
                              hipStream_t stream) {
  const float* img         = (const float*)d_in[0];
  const float* gt          = (const float*)d_in[1];
  const int*   line_prob   = (const int*)d_in[2];
  const float* sample_prob = (const float*)d_in[3];
  const float* att_w       = (const float*)d_in[4];
  // d_in[5] att_b: unused — softmax shift-invariance cancels it
  const float* w_ih        = (const float*)d_in[6];
  const float* w_hh        = (const float*)d_in[7];
  const float* b_ih        = (const float*)d_in[8];
  const float* b_hh        = (const float*)d_in[9];
  const float* lin1_w      = (const float*)d_in[10];
  const float* lin1_b      = (const float*)d_in[11];
  const float* lin2_w      = (const float*)d_in[12];
  const float* lin2_b      = (const float*)d_in[13];
  float* out = (float*)d_out;

  char* p = (char*)d_ws;
  auto alloc = [&](size_t bytes){ void* q = p; p += (bytes + 255) & ~(size_t)255; return q; };
  float*  gi_base   = (float*)alloc((size_t)B*G3*4);
  bf16_t* att_bf    = (bf16_t*)alloc((size_t)B*FEAT*2);
  bf16_t* sA        = (bf16_t*)alloc((size_t)54*CHW*2);
  bf16_t* sB        = (bf16_t*)alloc((size_t)16*CHW*2);
  bf16_t* sC        = (bf16_t*)alloc((size_t)2*CHW*2);
  bf16_t* w_ssn     = (bf16_t*)alloc((size_t)512*64*2);
  bf16_t* w_ih512b  = (bf16_t*)alloc((size_t)G3*512*2);
  float*  bias_comb = (float*)alloc((size_t)G3*4);

  prep4_kernel<<<4096, 256, 0, stream>>>(w_ih, w_hh, lin1_w, lin2_w, b_ih, b_hh,
                                         sA, sB, sC, w_ssn, w_ih512b, bias_comb);
  att_kernel<<<B, 256, 0, stream>>>(img, att_w, att_bf);
  gemm_mfma<<<dim3(G3/64, B/64), 256, 0, stream>>>(att_bf, w_ih512b, bias_comb, gi_base,
                                                   512, 512, 512, G3);
  mega11_kernel<<<NBLK, 512, 0, stream>>>(gi_base, sA, sB, sC, w_ssn, lin1_b, lin2_b,
                                          b_hh, gt, line_prob, sample_prob, out);
}

// Round 16
// 1117.418 us; speedup vs baseline: 1.9986x; 1.3491x over previous
//
#include <hip/hip_runtime.h>
#include <hip/hip_bf16.h>
#include <cstdint>

#define B 2048
#define NL 32
#define FEAT 512
#define HID 512
#define HW 64
#define OUTSZ 42
#define G3 1536
#define LDIH 554   // gru_w_ih row stride
#define MB 16      // batch rows per block
#define NBLK (B/MB)   // 128
#define LDX 584    // lds_x row stride
#define LDH 520    // o1s row stride
#define CPS 72     // chunks per step: 54 A + 16 B + 2 C
#define CHW 16384  // bf16 elements per 32KB chunk

typedef __bf16 bf16x8 __attribute__((ext_vector_type(8)));
typedef unsigned short u16x8 __attribute__((ext_vector_type(8)));
typedef float f32x4 __attribute__((ext_vector_type(4)));
typedef __hip_bfloat16 bf16_t;

#define MFMA(a,b,c) __builtin_amdgcn_mfma_f32_16x16x32_bf16(a,b,c,0,0,0)

// Per-wave pacing: wait until only the NEXT chunk's 4 loads are outstanding.
// No barrier — A/B phase ring traffic is wave-private.
#define WAITV4() asm volatile("s_waitcnt vmcnt(4)" ::: "memory")
// Phase boundary: publish this wave's ds ops, RAW barrier (prefetches stay in flight).
#define PHASE_SYNC() do {                                            \
    asm volatile("s_waitcnt lgkmcnt(0)" ::: "memory");               \
    __builtin_amdgcn_s_barrier();                                    \
  } while (0)
// Before phase C: C's 2 chunks are consumed cross-wave (waves 0-2 read all
// slices), so ALL waves' ring loads must have landed -> vmcnt(0) here only.
#define PHASE_SYNC_V0() do {                                         \
    asm volatile("s_waitcnt vmcnt(0) lgkmcnt(0)" ::: "memory");      \
    __builtin_amdgcn_s_barrier();                                    \
  } while (0)

static __device__ __forceinline__ float sigmoidf_(float x){ return 1.f/(1.f+__expf(-x)); }

static __device__ __forceinline__ void gld16(const bf16_t* g, bf16_t* l){
  __builtin_amdgcn_global_load_lds(
      (const __attribute__((address_space(1))) void*)g,
      (__attribute__((address_space(3))) void*)l, 16, 0, 0);
}

// ---------------- one-time weight prep into STAGING layouts (verified) ----------------
// sA[54][512][32]: chunk (k0,g) at c=k0*3+g; row rp; granule gq holds
//   k-quarter half = gq ^ ((rp>>1)&3)  -> conflict-free wave-wide ds_read_b128.
// sB[16][512][32]: lin1 chunks. sC[2][64][256]: lin2 k-halves, granule s holds
//   g = s^(j&7). w_ssn[512][64]; w_ih512b, bias_comb: preamble GEMM.
__global__ __launch_bounds__(256) void prep4_kernel(
    const float* __restrict__ w_ih, const float* __restrict__ w_hh,
    const float* __restrict__ lin1_w, const float* __restrict__ lin2_w,
    const float* __restrict__ b_ih, const float* __restrict__ b_hh,
    bf16_t* __restrict__ sA, bf16_t* __restrict__ sB, bf16_t* __restrict__ sC,
    bf16_t* __restrict__ w_ssn, bf16_t* __restrict__ w_ih512b,
    float* __restrict__ bias_comb){
  const int NA = 54*CHW, NB2 = 16*CHW, NC2 = 2*CHW, NS = 512*64, NI = G3*512;
  const int total = NA+NB2+NC2+NS+NI+G3;
  for (int idx = blockIdx.x*256 + threadIdx.x; idx < total; idx += gridDim.x*256){
    int i = idx;
    if (i < NA){
      int c = i/CHW, r2 = i%CHW, rp = r2>>5, kk = r2&31, gq = kk>>3, e = kk&7;
      int k0 = c/3, g = c%3;
      int half = gq ^ ((rp>>1)&3);
      int orow = g*512 + rp;
      int k = k0*32 + half*8 + e;
      float v = (k < 512) ? w_hh[orow*512 + k]
              : ((k < 512+OUTSZ && g < 2) ? w_ih[(size_t)orow*LDIH + k] : 0.f);
      sA[i] = __float2bfloat16(v);
    } else if ((i -= NA) < NB2){
      int c = i/CHW, r2 = i%CHW, rp = r2>>5, kk = r2&31, gq = kk>>3, e = kk&7;
      int half = gq ^ ((rp>>1)&3);
      sB[i] = __float2bfloat16(lin1_w[rp*512 + c*32 + half*8 + e]);
    } else if ((i -= NB2) < NC2){
      int n = i/CHW, r2 = i%CHW, j = r2>>8, kk = r2&255, s = kk>>3, e = kk&7;
      int g = s ^ (j & 7);
      int k = n*256 + g*8 + e;
      float v = (j < OUTSZ) ? lin2_w[j*512 + k] : 0.f;
      sC[i] = __float2bfloat16(v);
    } else if ((i -= NC2) < NS){
      int j = i>>6, k = i&63;
      float v = (k < OUTSZ) ? w_ih[(size_t)(1024+j)*LDIH + 512 + k] : 0.f;
      w_ssn[i] = __float2bfloat16(v);
    } else if ((i -= NS) < NI){
      int r = i>>9, c = i&511;
      w_ih512b[i] = __float2bfloat16(w_ih[(size_t)r*LDIH + c]);
    } else {
      int j = i - NI;
      bias_comb[j] = b_ih[j] + (j < 1024 ? b_hh[j] : 0.f);
    }
  }
}

// ---------------- attention precompute (step-invariant) ----------------
__global__ __launch_bounds__(256) void att_kernel(const float* __restrict__ feat,
                                                  const float* __restrict__ att_w,
                                                  bf16_t* __restrict__ att_feat){
  int b = blockIdx.x;
  const float* fb = feat + (size_t)b * FEAT * HW;
  __shared__ float part[4][64];
  __shared__ float attv[64];
  int t = threadIdx.x;
  int s = t & 63, q = t >> 6;
  float acc = 0.f;
  for (int c = q*128; c < q*128 + 128; ++c)
    acc = fmaf(fb[c*HW + s], att_w[c], acc);
  part[q][s] = acc;
  __syncthreads();
  if (t < 64){
    float v = part[0][t] + part[1][t] + part[2][t] + part[3][t];
    float m = v;
    for (int o = 32; o > 0; o >>= 1) m = fmaxf(m, __shfl_xor(m, o));
    float e = __expf(v - m);
    float ssum = e;
    for (int o = 32; o > 0; o >>= 1) ssum += __shfl_xor(ssum, o);
    attv[t] = e / ssum * 2.0f;   // * BETA
  }
  __syncthreads();
  for (int c = t; c < FEAT; c += 256){
    const float4* row = (const float4*)(fb + c*HW);
    float a2 = 0.f;
    #pragma unroll
    for (int k = 0; k < 16; ++k){
      float4 v4 = row[k];
      a2 = fmaf(v4.x, attv[k*4+0], a2);
      a2 = fmaf(v4.y, attv[k*4+1], a2);
      a2 = fmaf(v4.z, attv[k*4+2], a2);
      a2 = fmaf(v4.w, attv[k*4+3], a2);
    }
    att_feat[(size_t)b*FEAT + c] = __float2bfloat16(a2);
  }
}

// ---------------- bf16 MFMA GEMM (NT) for gi_base preamble ----------------
__global__ __launch_bounds__(256) void gemm_mfma(const bf16_t* __restrict__ A,
                                                 const bf16_t* __restrict__ W,
                                                 const float* __restrict__ bias,
                                                 float* __restrict__ C,
                                                 int K, int lda, int ldw, int ldc){
  const int tid = threadIdx.x;
  const int w = tid >> 6, lane = tid & 63;
  const int r = lane & 15, half = lane >> 4;
  const int m_base = blockIdx.y * 64;
  const int n_base = blockIdx.x * 64 + w * 16;
  const bf16_t* Ap = A + (size_t)(m_base + r)*lda + half*8;
  const bf16_t* Wp = W + (size_t)(n_base + r)*ldw + half*8;
  f32x4 acc[4] = {};
  for (int k0 = 0; k0 < K; k0 += 32){
    bf16x8 bfrag = *(const bf16x8*)(Wp + k0);
    #pragma unroll
    for (int i = 0; i < 4; ++i){
      bf16x8 afrag = *(const bf16x8*)(Ap + (size_t)i*16*lda + k0);
      acc[i] = MFMA(afrag, bfrag, acc[i]);
    }
  }
  const float bv = bias ? bias[n_base + r] : 0.f;
  #pragma unroll
  for (int i = 0; i < 4; ++i)
    #pragma unroll
    for (int q = 0; q < 4; ++q)
      C[(size_t)(m_base + i*16 + half*4 + q)*ldc + n_base + r] = acc[i][q] + bv;
}

// ---------------- the 32-step scan: wave-private ring, barrier-free chunk loop ----
// Fix vs round 15: NO issues inside phase C (they overwrote slot 1 while waves
// 0-2 cross-read chunk 70 from it). The two next-step prefetches are issued
// AFTER the step-final barrier, when slots 1,2's readers are provably drained.
__global__ __launch_bounds__(512, 2) void mega13_kernel(
    const float* __restrict__ gi_base,
    const bf16_t* __restrict__ sA,
    const bf16_t* __restrict__ sB,
    const bf16_t* __restrict__ sC,
    const bf16_t* __restrict__ w_ssn,
    const float* __restrict__ lin1_b,
    const float* __restrict__ lin2_b,
    const float* __restrict__ b_hh,
    const float* __restrict__ gt,
    const int* __restrict__ line_prob,
    const float* __restrict__ sample_prob,
    float* __restrict__ out){
  __shared__ bf16_t ring[3*CHW];         // 3 x 32KB, wave-sliced
  __shared__ bf16_t lds_x[MB][LDX];      // [h(512) | ss(42) | zeros]
  __shared__ bf16_t o1s[MB][LDH];
  const int tid = threadIdx.x;
  const int wv = tid >> 6, l = tid & 63;
  const int lr = l & 15, half = l >> 4;
  const int m0 = blockIdx.x * MB;
  const int colbase = wv * 64;
  const int rowoff = (colbase + lr)*32 + (half ^ ((lr >> 1) & 3))*8;  // in wave slice

  for (int i = tid; i < MB*LDX/2; i += 512) ((uint32_t*)lds_x)[i] = 0u;

  // ---- register-resident gi_base slice: 4(ti) x 4(q) x 3 gates ----
  float gir[4][4], giz[4][4], gin_[4][4];
  #pragma unroll
  for (int ti = 0; ti < 4; ++ti)
    #pragma unroll
    for (int q = 0; q < 4; ++q){
      const float* gp = gi_base + (size_t)(m0 + half*4 + q)*G3 + colbase + ti*16 + lr;
      gir[ti][q]  = gp[0];
      giz[ti][q]  = gp[512];
      gin_[ti][q] = gp[1024];
    }
  float bhn[4], lb1[4];
  #pragma unroll
  for (int ti = 0; ti < 4; ++ti){
    bhn[ti] = b_hh[1024 + colbase + ti*16 + lr];
    lb1[ti] = lin1_b[colbase + ti*16 + lr];
  }
  const int j3 = wv*16 + lr;
  const float b2c = (wv < 3 && j3 < OUTSZ) ? lin2_b[j3] : 0.f;
  bf16x8 sfr[4][2];
  #pragma unroll
  for (int ti = 0; ti < 4; ++ti)
    #pragma unroll
    for (int ks = 0; ks < 2; ++ks)
      sfr[ti][ks] = *(const bf16x8*)(w_ssn + (size_t)(colbase + ti*16 + lr)*64 + ks*32 + half*8);

  float hp[4][4] = {};

  // Per-wave slice issue: wave wv loads its elements [wv*2048, wv*2048+2048)
  // of chunk g into the same offsets of ring slot (g%3). 4 gld16 x 1KB.
  auto issue = [&](uint32_t g){
    const bf16_t* src = sA;              // dummy tail issues read sA
    if (g < (uint32_t)NL*CPS){
      uint32_t c = g % CPS;
      src = (c < 54) ? sA + (size_t)c*CHW
          : (c < 70) ? sB + (size_t)(c-54)*CHW
                     : sC + (size_t)(c-70)*CHW;
    }
    const int off = wv*2048 + l*8;
    const bf16_t* s = src + off;
    bf16_t* dst = ring + (g % 3)*CHW + off;
    #pragma unroll
    for (int i = 0; i < 4; ++i)
      gld16(s + i*512, dst + i*512);
  };

  __syncthreads();                       // lds_x zero visible (prologue only)
  uint32_t gc = 0;
  issue(0); issue(1);

  #pragma unroll 1
  for (int t = 0; t < NL; ++t){
    // ============ phase A: 54 chunks, barrier-free, per-wave paced ============
    f32x4 accA[3][4] = {};
    #pragma unroll 1
    for (int k0 = 0; k0 < 18; ++k0){
      bf16x8 a = *(const bf16x8*)&lds_x[lr][k0*32 + half*8];
      #pragma unroll
      for (int g = 0; g < 3; ++g){
        WAITV4();                        // own chunk-gc loads landed
        issue(gc + 2);                   // own slice of slot(gc-1): private, free
        const bf16_t* S = ring + (gc % 3)*CHW;
        #pragma unroll
        for (int ti = 0; ti < 4; ++ti){
          bf16x8 bf = *(const bf16x8*)&S[rowoff + ti*512];
          accA[g][ti] = MFMA(a, bf, accA[g][ti]);
        }
        ++gc;
      }
    }

    // ---- ssn (weights in VGPRs; reads lds_x ss cols) ----
    f32x4 accS[4] = {};
    #pragma unroll
    for (int ks = 0; ks < 2; ++ks){
      bf16x8 a2 = *(const bf16x8*)&lds_x[lr][512 + ks*32 + half*8];
      #pragma unroll
      for (int ti = 0; ti < 4; ++ti)
        accS[ti] = MFMA(a2, sfr[ti][ks], accS[ti]);
    }
    PHASE_SYNC();    // (1) all waves' lds_x reads done before gates rewrite h

    // ---- gates ----
    #pragma unroll
    for (int ti = 0; ti < 4; ++ti)
      #pragma unroll
      for (int q = 0; q < 4; ++q){
        float ir = accA[0][ti][q] + gir[ti][q];
        float iz = accA[1][ti][q] + giz[ti][q];
        float hn = accA[2][ti][q] + bhn[ti];
        float gn = gin_[ti][q] + accS[ti][q];
        float r = sigmoidf_(ir);
        float z = sigmoidf_(iz);
        float n = tanhf(gn + r*hn);
        float hv = (1.f - z)*n + z*hp[ti][q];
        hp[ti][q] = hv;
        lds_x[half*4 + q][colbase + ti*16 + lr] = __float2bfloat16(hv);
      }
    PHASE_SYNC();    // (2) h visible to all waves

    // ============ phase B: 16 chunks, barrier-free, per-wave paced ============
    f32x4 accB[4] = {};
    #pragma unroll 1
    for (int cb = 0; cb < 16; ++cb){
      WAITV4();
      issue(gc + 2);                     // chunks 56..71: A/B slots, wave-private
      union { u16x8 u; bf16x8 b; } va;
      va.u = *(const u16x8*)&lds_x[lr][cb*32 + half*8];
      #pragma unroll
      for (int e = 0; e < 8; ++e)
        if (va.u[e] & 0x8000) va.u[e] = 0;       // relu on bf16 sign
      const bf16_t* S = ring + (gc % 3)*CHW;
      #pragma unroll
      for (int ti = 0; ti < 4; ++ti){
        bf16x8 bf = *(const bf16x8*)&S[rowoff + ti*512];
        accB[ti] = MFMA(va.b, bf, accB[ti]);
      }
      ++gc;
    }
    #pragma unroll
    for (int ti = 0; ti < 4; ++ti)
      #pragma unroll
      for (int q = 0; q < 4; ++q)
        o1s[half*4 + q][colbase + ti*16 + lr] =
            __float2bfloat16(fmaxf(accB[ti][q] + lb1[ti], 0.f));
    PHASE_SYNC_V0(); // (3) o1s visible AND all waves' C-chunk loads landed
                     //     (C chunks are consumed cross-slice by waves 0-2)

    // ============ phase C: 2 chunks (lin2), pre-drained, NO ISSUES ============
    // (round-15 bug: issuing here overwrote slot 1 while waves 0-2 read it)
    f32x4 accC = {};
    #pragma unroll
    for (int n = 0; n < 2; ++n){
      if (wv < 3){
        const bf16_t* S = ring + (gc % 3)*CHW;
        #pragma unroll
        for (int k0 = 0; k0 < 8; ++k0){
          bf16x8 a = *(const bf16x8*)&o1s[lr][(n*8 + k0)*32 + half*8];
          int sg = (k0*4 + half) ^ (j3 & 7);
          bf16x8 bf = *(const bf16x8*)&S[j3*256 + sg*8];
          accC = MFMA(a, bf, accC);
        }
      }
      ++gc;
    }
    // outputs + ss_{t+1}
    if (wv < 3){
      #pragma unroll
      for (int q = 0; q < 4; ++q){
        float val = accC[q] + b2c;
        int row = half*4 + q;
        int bm = m0 + row;
        if (j3 < 40){
          out[((size_t)bm*NL + t)*40 + j3] = val;
        } else if (j3 < 42){
          float other = __shfl_xor(val, 1);
          float mx = fmaxf(val, other);
          float e0 = __expf(val - mx), e1 = __expf(other - mx);
          out[(size_t)B*NL*40 + ((size_t)bm*NL + t)*2 + (j3 - 40)] = e0/(e0 + e1);
        }
        if (t + 1 < NL && j3 < OUTSZ){
          bool up = sample_prob[(size_t)(t+1)*B + bm] < 0.1f;
          float gtv;
          if (j3 < 40) gtv = gt[((size_t)bm*NL + t)*40 + j3];
          else {
            float pv = (float)line_prob[bm*NL + t];
            gtv = (j3 == 40) ? 1.f - pv : pv;
          }
          lds_x[row][512 + j3] = __float2bfloat16(up ? val : gtv);
        }
      }
    }
    PHASE_SYNC();    // (4) ss visible; C readers drained -> slots 1,2 free
    issue(gc);       // next step's chunk 0 (slot 0; chunk 69's own-slice freed)
    issue(gc + 1);   // next step's chunk 1 (slot 1; chunk 70 readers drained)
  }
}

extern "C" void kernel_launch(void* const* d_in, const int* in_sizes, int n_in,
                              void* d_out, int out_size, void* d_ws, size_t ws_size,
                              hipStream_t stream) {
  const float* img         = (const float*)d_in[0];
  const float* gt          = (const float*)d_in[1];
  const int*   line_prob   = (const int*)d_in[2];
  const float* sample_prob = (const float*)d_in[3];
  const float* att_w       = (const float*)d_in[4];
  // d_in[5] att_b: unused — softmax shift-invariance cancels it
  const float* w_ih        = (const float*)d_in[6];
  const float* w_hh        = (const float*)d_in[7];
  const float* b_ih        = (const float*)d_in[8];
  const float* b_hh        = (const float*)d_in[9];
  const float* lin1_w      = (const float*)d_in[10];
  const float* lin1_b      = (const float*)d_in[11];
  const float* lin2_w      = (const float*)d_in[12];
  const float* lin2_b      = (const float*)d_in[13];
  float* out = (float*)d_out;

  char* p = (char*)d_ws;
  auto alloc = [&](size_t bytes){ void* q = p; p += (bytes + 255) & ~(size_t)255; return q; };
  float*  gi_base   = (float*)alloc((size_t)B*G3*4);
  bf16_t* att_bf    = (bf16_t*)alloc((size_t)B*FEAT*2);
  bf16_t* sA        = (bf16_t*)alloc((size_t)54*CHW*2);
  bf16_t* sB        = (bf16_t*)alloc((size_t)16*CHW*2);
  bf16_t* sC        = (bf16_t*)alloc((size_t)2*CHW*2);
  bf16_t* w_ssn     = (bf16_t*)alloc((size_t)512*64*2);
  bf16_t* w_ih512b  = (bf16_t*)alloc((size_t)G3*512*2);
  float*  bias_comb = (float*)alloc((size_t)G3*4);

  prep4_kernel<<<4096, 256, 0, stream>>>(w_ih, w_hh, lin1_w, lin2_w, b_ih, b_hh,
                                         sA, sB, sC, w_ssn, w_ih512b, bias_comb);
  att_kernel<<<B, 256, 0, stream>>>(img, att_w, att_bf);
  gemm_mfma<<<dim3(G3/64, B/64), 256, 0, stream>>>(att_bf, w_ih512b, bias_comb, gi_base,
                                                   512, 512, 512, G3);
  mega13_kernel<<<NBLK, 512, 0, stream>>>(gi_base, sA, sB, sC, w_ssn, lin1_b, lin2_b,
                                          b_hh, gt, line_prob, sample_prob, out);
}